// Round 2
// 3201.576 us; speedup vs baseline: 1.1706x; 1.1706x over previous
//
#include <hip/hip_runtime.h>
#include <cstdint>
#include <cstddef>

// ---------------------------------------------------------------------------
// NodeLayer1: 4x GATv2 conv -> fuse GEMM -> edge LN+MLP -> gather
// Dims: N=50000, D=128, H=16, C=8 (H*C=128), E1=500000, E2=500000, E3=250000,
// E4=125000. Outputs: xf [N,128], edge_attr_new [E1,128], dual_out [400000,128]
//
// All dense GEMMs (12 node GEMMs + edge MLP) on v_mfma_f32_16x16x32_bf16 with
// bf16x3 splitting (hi/lo decomposition, 3 MFMAs per product term) ->
// ~2^-16 relative error, far below tolerance. Weights pre-packed once per
// launch into the exact B-fragment layout (hi plane + lo plane).
// (Resubmission of round-1 kernel: round-1 bench died at container level with
// no kernel signal; OOB/hang audit found nothing. Unchanged for attribution.)
// ---------------------------------------------------------------------------

#define NEG_SLOPE 0.2f

typedef __attribute__((ext_vector_type(8))) short short8v;  // 8 x bf16 (4 VGPR)
typedef __attribute__((ext_vector_type(4))) float f32x4v;   // MFMA acc

// ordered-uint encoding so unsigned atomicMax == float max
__device__ __forceinline__ unsigned fenc(float f) {
  unsigned u = __float_as_uint(f);
  return (u & 0x80000000u) ? ~u : (u | 0x80000000u);
}
__device__ __forceinline__ float fdec(unsigned k) {
  unsigned u = (k & 0x80000000u) ? (k & 0x7FFFFFFFu) : ~k;
  return __uint_as_float(u);
}

// f32 -> bf16 hi (truncate) + bf16 lo (residual). hi+lo captures ~16 mantissa
// bits; dropping lo*lo in products leaves ~2^-16 relative error.
__device__ __forceinline__ void cvt_bf16x2(float f, short& h, short& l) {
  unsigned u = __float_as_uint(f);
  h = (short)(u >> 16);
  float fh = __uint_as_float(u & 0xFFFF0000u);
  l = (short)(__float_as_uint(f - fh) >> 16);
}

// ---------------------------------------------------------------------------
// Pack 13 weight matrices (12x K=128, 1x K=256; all row-major [K][128] fp32)
// into MFMA B-fragment layout, bf16 hi plane then lo plane per segment.
// Fragment element (s,ct,l,j) = W[s*32 + (l>>4)*8 + j][ct*16 + (l&15)].
// Linear index i = ((s*8+ct)*64 + l)*8 + j  -> a wave's 64 lanes read 1KB
// contiguous per (s,ct): perfectly coalesced, conflict-free.
// Segment sg at out + sg*32768 shorts (seg 12 = mlp_W uses 65536).
// ---------------------------------------------------------------------------
struct PackArgs { const float* w[13]; };

__global__ __launch_bounds__(256) void pack_all(PackArgs pa, short* __restrict__ out)
{
  const int seg = blockIdx.y;
  const int K = (seg == 12) ? 256 : 128;
  const int total = K * 128;
  int i = blockIdx.x * 256 + threadIdx.x;
  if (i >= total) return;
  int j  = i & 7;
  int l  = (i >> 3) & 63;
  int ct = (i >> 9) & 7;
  int s  = i >> 12;
  int row = s * 32 + (l >> 4) * 8 + j;
  int col = ct * 16 + (l & 15);
  float v = pa.w[seg][row * 128 + col];
  short h, lo;
  cvt_bf16x2(v, h, lo);
  short* oseg = out + (size_t)seg * 32768;
  oseg[i] = h;
  oseg[total + i] = lo;
}

// ---------------------------------------------------------------------------
// out[M,128] = (A[M,128] + biasA) @ W[128,128]   (optional accumulate)
// 32 rows/block, 128 threads (2 waves). bf16x3 MFMA.
// ---------------------------------------------------------------------------
__global__ __launch_bounds__(128) void gemm_mfma_n(
    const float* __restrict__ A, const short* __restrict__ Wp,
    const float* __restrict__ biasA, float* __restrict__ out,
    int M, int accumulate)
{
  __shared__ __align__(16) short Ah[32][136];   // +8 pad: 2-way banks on b128
  __shared__ __align__(16) short Al[32][136];
  const int t = threadIdx.x;
  const int row0 = blockIdx.x * 32;

  // stage + convert: thread (rg,cg) loads float4s, 4 rows in parallel
  const int cg = t & 31, rg = t >> 5;
  float4 b4 = make_float4(0.f, 0.f, 0.f, 0.f);
  if (biasA) b4 = *(const float4*)&biasA[cg * 4];
#pragma unroll
  for (int rr = 0; rr < 8; ++rr) {
    int r = rr * 4 + rg;
    int row = row0 + r;
    float4 v = make_float4(0.f, 0.f, 0.f, 0.f);
    if (row < M) v = *(const float4*)&A[(size_t)row * 128 + cg * 4];
    v.x += b4.x; v.y += b4.y; v.z += b4.z; v.w += b4.w;
    short h0, h1, h2, h3, l0, l1, l2, l3;
    cvt_bf16x2(v.x, h0, l0); cvt_bf16x2(v.y, h1, l1);
    cvt_bf16x2(v.z, h2, l2); cvt_bf16x2(v.w, h3, l3);
    *(short4*)&Ah[r][cg * 4] = make_short4(h0, h1, h2, h3);
    *(short4*)&Al[r][cg * 4] = make_short4(l0, l1, l2, l3);
  }
  __syncthreads();

  const int l = t & 63, w = t >> 6;
  const int lr = l & 15, lg = l >> 4;
  f32x4v acc[8] = {};
  const short* WpLo = Wp + 128 * 128;
#pragma unroll
  for (int s = 0; s < 4; ++s) {
    short8v ah = *(const short8v*)&Ah[w * 16 + lr][s * 32 + lg * 8];
    short8v al = *(const short8v*)&Al[w * 16 + lr][s * 32 + lg * 8];
#pragma unroll
    for (int ct = 0; ct < 8; ++ct) {
      int fo = ((s * 8 + ct) * 64 + l) * 8;
      short8v wh = *(const short8v*)(Wp + fo);
      short8v wl = *(const short8v*)(WpLo + fo);
      acc[ct] = __builtin_amdgcn_mfma_f32_16x16x32_bf16(ah, wh, acc[ct], 0, 0, 0);
      acc[ct] = __builtin_amdgcn_mfma_f32_16x16x32_bf16(al, wh, acc[ct], 0, 0, 0);
      acc[ct] = __builtin_amdgcn_mfma_f32_16x16x32_bf16(ah, wl, acc[ct], 0, 0, 0);
    }
  }
  // C/D layout (m89-verified): col = lane&15, row = (lane>>4)*4 + reg
#pragma unroll
  for (int ct = 0; ct < 8; ++ct) {
#pragma unroll
    for (int q = 0; q < 4; ++q) {
      int row = row0 + w * 16 + lg * 4 + q;
      if (row < M) {
        size_t o = (size_t)row * 128 + ct * 16 + lr;
        float v = acc[ct][q];
        out[o] = accumulate ? (out[o] + v) : v;
      }
    }
  }
}

// ---------------------------------------------------------------------------
// edge MLP fused: gather pair=[xf[src],xf[dst]] -> LN (register-resident,
// 4 lanes/edge) -> ReLU -> bf16x3 MFMA GEMM [32,256]@[256,128] ->
// out = edge_attr + result + mlp_b.  32 edges/block, 128 threads.
// ---------------------------------------------------------------------------
__global__ __launch_bounds__(128) void edge_mlp_mfma(
    const float* __restrict__ xf,
    const int* __restrict__ src, const int* __restrict__ dst,
    const float* __restrict__ ln_g, const float* __restrict__ ln_b,
    const short* __restrict__ Wp, const float* __restrict__ mlp_b,
    const float* __restrict__ edge_attr, float* __restrict__ out, int E)
{
  __shared__ __align__(16) short Ah[32][264];   // 256 + 8 pad
  __shared__ __align__(16) short Al[32][264];
  __shared__ float sg[256], sb[256];
  __shared__ int sidx[32], didx[32];
  const int t = threadIdx.x;
  const int e0 = blockIdx.x * 32;

  if (t < 32) {
    int e = e0 + t;
    sidx[t] = (e < E) ? src[e] : src[0];
    didx[t] = (e < E) ? dst[e] : dst[0];
  }
  sg[t] = ln_g[t];       sg[128 + t] = ln_g[128 + t];
  sb[t] = ln_b[t];       sb[128 + t] = ln_b[128 + t];
  __syncthreads();

  // gather: 4 threads per edge, consecutive threads -> consecutive float4
  const int r = t >> 2, j = t & 3;
  const float* prs = xf + (size_t)sidx[r] * 128;
  const float* prd = xf + (size_t)didx[r] * 128;
  float4 va[8], vb[8];
#pragma unroll
  for (int m = 0; m < 8; ++m) {
    va[m] = *(const float4*)(prs + (m * 4 + j) * 4);
    vb[m] = *(const float4*)(prd + (m * 4 + j) * 4);
  }
  float s1 = 0.f, s2 = 0.f;
#pragma unroll
  for (int m = 0; m < 8; ++m) {
    s1 += va[m].x + va[m].y + va[m].z + va[m].w;
    s1 += vb[m].x + vb[m].y + vb[m].z + vb[m].w;
    s2 += va[m].x * va[m].x + va[m].y * va[m].y + va[m].z * va[m].z + va[m].w * va[m].w;
    s2 += vb[m].x * vb[m].x + vb[m].y * vb[m].y + vb[m].z * vb[m].z + vb[m].w * vb[m].w;
  }
  s1 += __shfl_xor(s1, 1); s1 += __shfl_xor(s1, 2);
  s2 += __shfl_xor(s2, 1); s2 += __shfl_xor(s2, 2);
  const float mu = s1 * (1.f / 256.f);
  const float var = s2 * (1.f / 256.f) - mu * mu;
  const float rs = rsqrtf(var + 1e-5f);

  // normalize + relu + convert -> LDS (short4 = 8B writes)
#pragma unroll
  for (int m = 0; m < 8; ++m) {
    const int c4 = (m * 4 + j) * 4;
#pragma unroll
    for (int half = 0; half < 2; ++half) {
      const float4 v = half ? vb[m] : va[m];
      const int k = half * 128 + c4;
      float el[4] = {v.x, v.y, v.z, v.w};
      short h[4], lo[4];
#pragma unroll
      for (int u = 0; u < 4; ++u) {
        float f = (el[u] - mu) * rs * sg[k + u] + sb[k + u];
        f = f > 0.f ? f : 0.f;
        cvt_bf16x2(f, h[u], lo[u]);
      }
      *(short4*)&Ah[r][k] = make_short4(h[0], h[1], h[2], h[3]);
      *(short4*)&Al[r][k] = make_short4(lo[0], lo[1], lo[2], lo[3]);
    }
  }
  __syncthreads();

  const int l = t & 63, w = t >> 6;
  const int lr = l & 15, lg = l >> 4;
  f32x4v acc[8] = {};
  const short* WpLo = Wp + 256 * 128;
  for (int s = 0; s < 8; ++s) {
    short8v ah = *(const short8v*)&Ah[w * 16 + lr][s * 32 + lg * 8];
    short8v al = *(const short8v*)&Al[w * 16 + lr][s * 32 + lg * 8];
#pragma unroll
    for (int ct = 0; ct < 8; ++ct) {
      int fo = ((s * 8 + ct) * 64 + l) * 8;
      short8v wh = *(const short8v*)(Wp + fo);
      short8v wl = *(const short8v*)(WpLo + fo);
      acc[ct] = __builtin_amdgcn_mfma_f32_16x16x32_bf16(ah, wh, acc[ct], 0, 0, 0);
      acc[ct] = __builtin_amdgcn_mfma_f32_16x16x32_bf16(al, wh, acc[ct], 0, 0, 0);
      acc[ct] = __builtin_amdgcn_mfma_f32_16x16x32_bf16(ah, wl, acc[ct], 0, 0, 0);
    }
  }
#pragma unroll
  for (int ct = 0; ct < 8; ++ct) {
    const int col = ct * 16 + lr;
    const float mb = mlp_b[col];
#pragma unroll
    for (int q = 0; q < 4; ++q) {
      int e = e0 + w * 16 + lg * 4 + q;
      if (e < E)
        out[(size_t)e * 128 + col] =
            edge_attr[(size_t)e * 128 + col] + acc[ct][q] + mb;
    }
  }
}

// ---------------------------------------------------------------------------
// conv1 logits: m = xl[src] + xr[dst] + dual_attr[e] @ We ; leaky_relu; dot att
// 16 edges per block, 128 threads. (fp32 VALU path — MFMA conversion next.)
// ---------------------------------------------------------------------------
__global__ __launch_bounds__(128) void logits_conv1(
    const float* __restrict__ xl, const float* __restrict__ xr,
    const int* __restrict__ src, const int* __restrict__ dst,
    const float* __restrict__ dualA, const float* __restrict__ We,
    const float* __restrict__ att,
    float* __restrict__ ebuf, unsigned* __restrict__ nmax, int E)
{
  __shared__ __align__(16) float lds[16 * 128];
  __shared__ int sidx[16], didx[16];
  const int t = threadIdx.x;
  const int e0 = blockIdx.x * 16;

  for (int r = 0; r < 16; ++r) {
    int e = e0 + r;
    lds[r * 128 + t] = (e < E) ? dualA[(size_t)e * 128 + t] : 0.f;
  }
  if (t < 16) {
    int e = e0 + t;
    sidx[t] = (e < E) ? src[e] : 0;
    didx[t] = (e < E) ? dst[e] : 0;
  }
  __syncthreads();

  float acc[16];
#pragma unroll
  for (int r = 0; r < 16; ++r) acc[r] = 0.f;
  for (int k = 0; k < 128; k += 4) {
    float w0 = We[(k + 0) * 128 + t];
    float w1 = We[(k + 1) * 128 + t];
    float w2 = We[(k + 2) * 128 + t];
    float w3 = We[(k + 3) * 128 + t];
#pragma unroll
    for (int r = 0; r < 16; ++r) {
      const float4 v = *(const float4*)&lds[r * 128 + k];
      acc[r] += v.x * w0 + v.y * w1 + v.z * w2 + v.w * w3;
    }
  }

  const float a_t = att[t];
  const int h = t >> 3;
  for (int r = 0; r < 16; ++r) {
    int e = e0 + r;
    if (e >= E) break;
    float m = acc[r] + xl[(size_t)sidx[r] * 128 + t] + xr[(size_t)didx[r] * 128 + t];
    float lr = (m > 0.f) ? m : NEG_SLOPE * m;
    float v = lr * a_t;
    v += __shfl_down(v, 4, 8);
    v += __shfl_down(v, 2, 8);
    v += __shfl_down(v, 1, 8);
    if ((t & 7) == 0) {
      ebuf[(size_t)e * 16 + h] = v;
      atomicMax(&nmax[(size_t)didx[r] * 16 + h], fenc(v));
    }
  }
}

// ---------------------------------------------------------------------------
// conv2..4 logits (no edge attr). One edge per block (128 threads).
// ---------------------------------------------------------------------------
__global__ __launch_bounds__(128) void logits_plain(
    const float* __restrict__ xl, const float* __restrict__ xr,
    const int* __restrict__ src, const int* __restrict__ dst,
    const float* __restrict__ att,
    float* __restrict__ ebuf, unsigned* __restrict__ nmax, int E)
{
  const int e = blockIdx.x;
  const int t = threadIdx.x;
  const int s = src[e], d = dst[e];
  float m = xl[(size_t)s * 128 + t] + xr[(size_t)d * 128 + t];
  float lr = (m > 0.f) ? m : NEG_SLOPE * m;
  float v = lr * att[t];
  v += __shfl_down(v, 4, 8);
  v += __shfl_down(v, 2, 8);
  v += __shfl_down(v, 1, 8);
  if ((t & 7) == 0) {
    int h = t >> 3;
    ebuf[(size_t)e * 16 + h] = v;
    atomicMax(&nmax[(size_t)d * 16 + h], fenc(v));
  }
}

// ---------------------------------------------------------------------------
// exp(logit - max[dst]) in place, atomicAdd into nsum. one thread per (e,h)
// ---------------------------------------------------------------------------
__global__ __launch_bounds__(256) void exp_sum(
    const int* __restrict__ dst, float* __restrict__ ebuf,
    const unsigned* __restrict__ nmax, float* __restrict__ nsum, int E)
{
  int i = blockIdx.x * 256 + threadIdx.x;
  if (i >= E * 16) return;
  int e = i >> 4, h = i & 15;
  int d = dst[e];
  float m = fdec(nmax[(size_t)d * 16 + h]);
  float ex = expf(ebuf[i] - m);
  ebuf[i] = ex;
  atomicAdd(&nsum[(size_t)d * 16 + h], ex);
}

// ---------------------------------------------------------------------------
// xc[dst] += alpha * xl[src]. one thread per (e, feature t).
// ---------------------------------------------------------------------------
__global__ __launch_bounds__(256) void aggregate(
    const int* __restrict__ src, const int* __restrict__ dst,
    const float* __restrict__ ebuf, const float* __restrict__ nsum,
    const float* __restrict__ xl, float* __restrict__ xc, int E)
{
  long long i = (long long)blockIdx.x * 256 + threadIdx.x;
  if (i >= (long long)E * 128) return;
  int e = (int)(i >> 7), t = (int)(i & 127), h = t >> 3;
  int s = src[e], d = dst[e];
  float alpha = ebuf[(size_t)e * 16 + h] / (nsum[(size_t)d * 16 + h] + 1e-16f);
  atomicAdd(&xc[(size_t)d * 128 + t], alpha * xl[(size_t)s * 128 + t]);
}

// ---------------------------------------------------------------------------
// xf init: xf[i] = fuse_b[i%128]
// ---------------------------------------------------------------------------
__global__ __launch_bounds__(256) void init_xf(
    float* __restrict__ xf, const float* __restrict__ fb, int total)
{
  int i = blockIdx.x * 256 + threadIdx.x;
  if (i < total) xf[i] = fb[i & 127];
}

// ---------------------------------------------------------------------------
// dual_out[i] = (oemap[i] < E) ? edge_attr_new[oemap[i]] : ones
// ---------------------------------------------------------------------------
__global__ __launch_bounds__(256) void gather_dual(
    const int* __restrict__ idx, const float* __restrict__ ean,
    float* __restrict__ out, int M, int E)
{
  long long i = (long long)blockIdx.x * 256 + threadIdx.x;
  if (i >= (long long)M * 128) return;
  int row = (int)(i >> 7), t = (int)(i & 127);
  int r = idx[row];
  out[i] = (r < E) ? ean[(size_t)r * 128 + t] : 1.0f;
}

// ---------------------------------------------------------------------------

extern "C" void kernel_launch(void* const* d_in, const int* in_sizes, int n_in,
                              void* d_out, int out_size, void* d_ws, size_t ws_size,
                              hipStream_t stream)
{
  const float* x         = (const float*)d_in[0];
  const int*   ei[4]     = {(const int*)d_in[1], (const int*)d_in[2],
                            (const int*)d_in[3], (const int*)d_in[4]};
  const float* dual_attr = (const float*)d_in[5];
  const float* edge_attr = (const float*)d_in[6];
  const int*   oemap     = (const int*)d_in[7];
  const float* Wl[4]  = {(const float*)d_in[8],  (const float*)d_in[12],
                         (const float*)d_in[16], (const float*)d_in[20]};
  const float* Wr[4]  = {(const float*)d_in[9],  (const float*)d_in[13],
                         (const float*)d_in[17], (const float*)d_in[21]};
  const float* att[4] = {(const float*)d_in[10], (const float*)d_in[14],
                         (const float*)d_in[18], (const float*)d_in[22]};
  const float* bc[4]  = {(const float*)d_in[11], (const float*)d_in[15],
                         (const float*)d_in[19], (const float*)d_in[23]};
  const float* We1    = (const float*)d_in[24];
  const float* fuse_W = (const float*)d_in[25];
  const float* fuse_b = (const float*)d_in[26];
  const float* ln_g   = (const float*)d_in[27];
  const float* ln_b   = (const float*)d_in[28];
  const float* mlp_W  = (const float*)d_in[29];
  const float* mlp_b  = (const float*)d_in[30];

  const int N  = in_sizes[0] / 128;
  int E[4];
  for (int c = 0; c < 4; ++c) E[c] = in_sizes[1 + c] / 2;
  const int Moe = in_sizes[7];

  // workspace layout: packed weights (shorts) first, then float buffers
  // segments 0..3: Wl, 4..7: Wr, 8..11: fuse slices (K=128, 32768 shorts each)
  // segment 12: mlp_W (K=256, 65536 shorts). total 458752 shorts = 896 KB.
  short* wp = (short*)d_ws;
  float* ws = (float*)(wp + 458752);
  float* xl    = ws;                       // N*128
  float* xr    = xl + (size_t)N * 128;     // N*128
  float* xc    = xr + (size_t)N * 128;     // N*128
  float* ebuf  = xc + (size_t)N * 128;     // Emax*16
  unsigned* nmax = (unsigned*)(ebuf + (size_t)E[0] * 16); // N*16
  float* nsum  = (float*)(nmax + (size_t)N * 16);         // N*16

  // output layout
  float* xf      = (float*)d_out;                 // N*128
  float* ean     = xf + (size_t)N * 128;          // E1*128
  float* dualout = ean + (size_t)E[0] * 128;      // Moe*128

  const int rowBlocks32 = (N + 31) / 32;

  // pack all 13 weight matrices into MFMA fragment layout (one launch)
  PackArgs pa;
  for (int c = 0; c < 4; ++c) {
    pa.w[c]     = Wl[c];
    pa.w[4 + c] = Wr[c];
    pa.w[8 + c] = fuse_W + (size_t)c * 128 * 128;
  }
  pa.w[12] = mlp_W;
  pack_all<<<dim3(128, 13), 256, 0, stream>>>(pa, wp);

  // xf = fuse_b (accumulated into below)
  init_xf<<<(N * 128 + 255) / 256, 256, 0, stream>>>(xf, fuse_b, N * 128);

  for (int c = 0; c < 4; ++c) {
    const int* src = ei[c];
    const int* dst = ei[c] + E[c];

    gemm_mfma_n<<<rowBlocks32, 128, 0, stream>>>(
        x, wp + (size_t)c * 32768, nullptr, xl, N, 0);
    gemm_mfma_n<<<rowBlocks32, 128, 0, stream>>>(
        x, wp + (size_t)(4 + c) * 32768, nullptr, xr, N, 0);

    hipMemsetAsync(xc,   0, (size_t)N * 128 * sizeof(float), stream);
    hipMemsetAsync(nmax, 0, (size_t)N * 16 * sizeof(unsigned), stream);
    hipMemsetAsync(nsum, 0, (size_t)N * 16 * sizeof(float), stream);

    if (c == 0) {
      logits_conv1<<<(E[c] + 15) / 16, 128, 0, stream>>>(
          xl, xr, src, dst, dual_attr, We1, att[c], ebuf, nmax, E[c]);
    } else {
      logits_plain<<<E[c], 128, 0, stream>>>(
          xl, xr, src, dst, att[c], ebuf, nmax, E[c]);
    }

    exp_sum<<<(E[c] * 16 + 255) / 256, 256, 0, stream>>>(dst, ebuf, nmax, nsum, E[c]);

    aggregate<<<(int)(((long long)E[c] * 128 + 255) / 256), 256, 0, stream>>>(
        src, dst, ebuf, nsum, xl, xc, E[c]);

    // xf += (xc + b_c) @ fuse_W[c*128:(c+1)*128, :]
    gemm_mfma_n<<<rowBlocks32, 128, 0, stream>>>(
        xc, wp + (size_t)(8 + c) * 32768, bc[c], xf, N, 1);
  }

  edge_mlp_mfma<<<(E[0] + 31) / 32, 128, 0, stream>>>(
      xf, ei[0], ei[0] + E[0], ln_g, ln_b, wp + 12 * 32768, mlp_b,
      edge_attr, ean, E[0]);

  gather_dual<<<(int)(((long long)Moe * 128 + 255) / 256), 256, 0, stream>>>(
      oemap, ean, dualout, Moe, E[0]);
}